// Round 1
// baseline (806.402 us; speedup 1.0000x reference)
//
#include <hip/hip_runtime.h>
#include <hip/hip_bf16.h>
#include <math.h>

// MoE FFN: T=2048 tokens, H=1024, F=2816, E=8, top-2, SwiGLU + aux loss.
// Strategy: fp32->bf16 convert (+transpose weights to [N][K]) once per call,
// then two gathered per-expert MFMA GEMMs (m9x "gemm_bt" structure).

#define T_TOK 2048
#define HID   1024
#define DFF   2816
#define NE    8
#define ROWS  4096   // T_TOK * TOP_K

typedef unsigned short u16;
typedef __attribute__((ext_vector_type(8))) short bf16x8;  // 8 bf16 in 4 VGPRs (per guide)
typedef __attribute__((ext_vector_type(4))) float f32x4;

// ---- workspace layout (bytes) ----
#define OFF_CNT    0                       // int[8]
#define OFF_IMP    64                      // float[8]
#define OFF_OFFS   128                     // int[8]
#define OFF_TOPKI  256                     // int[4096]
#define OFF_TOPKP  (OFF_TOPKI + 16384)     // float[4096]
#define OFF_BTOK   (OFF_TOPKP + 16384)     // int[8][2048]
#define OFF_BPRB   (OFF_BTOK + 65536)      // float[8][2048]
#define OFF_XB     (OFF_BPRB + 65536)      // bf16[2048][1024]   (16B aligned)
#define OFF_W1T    (OFF_XB + 4194304)      // bf16[8][2816][1024]  (transposed)
#define OFF_W3T    (OFF_W1T + 46137344)
#define OFF_W2T    (OFF_W3T + 46137344)    // bf16[8][1024][2816]  (transposed)
#define OFF_ACT    (OFF_W2T + 46137344)    // bf16[4096][2816]
#define WS_NEEDED  (OFF_ACT + 23068672)    // ~158.2 MiB

__device__ __forceinline__ u16 f2bf(float f) {
    unsigned u = __float_as_uint(f);
    u = (u + 0x7fffu + ((u >> 16) & 1u)) >> 16;   // RNE
    return (u16)u;
}

// ---- fp32 -> bf16, x (no transpose) ----
__global__ void cvt_x_kernel(const float* __restrict__ x, u16* __restrict__ xb) {
    int i = blockIdx.x * 256 + threadIdx.x;          // over float4s
    float4 v = ((const float4*)x)[i];
    union { u16 s[4]; unsigned long long q; } o;
    o.s[0] = f2bf(v.x); o.s[1] = f2bf(v.y); o.s[2] = f2bf(v.z); o.s[3] = f2bf(v.w);
    ((unsigned long long*)xb)[i] = o.q;
}

// ---- fp32 [K][N] -> bf16 [N][K] transpose (per expert in grid.z) ----
__global__ void transpose_kernel(const float* __restrict__ in, u16* __restrict__ out,
                                 int K, int N) {
    __shared__ float tile[64][65];
    const float* ip = in + (size_t)blockIdx.z * K * N;
    u16* op = out + (size_t)blockIdx.z * K * N;
    int n0 = blockIdx.x * 64, k0 = blockIdx.y * 64;
    int tid = threadIdx.x;
#pragma unroll
    for (int p = 0; p < 4; ++p) {
        int row = p * 16 + (tid >> 4);       // k-local
        int v = (tid & 15) * 4;              // n-local
        float4 d = *(const float4*)(ip + (size_t)(k0 + row) * N + n0 + v);
        tile[row][v] = d.x; tile[row][v + 1] = d.y; tile[row][v + 2] = d.z; tile[row][v + 3] = d.w;
    }
    __syncthreads();
#pragma unroll
    for (int p = 0; p < 2; ++p) {
        int n = p * 32 + (tid >> 3);         // n-local
        int g = (tid & 7) * 8;               // k-local chunk
        u16 o[8];
#pragma unroll
        for (int j = 0; j < 8; ++j) o[j] = f2bf(tile[g + j][n]);
        *(bf16x8*)(op + (size_t)(n0 + n) * K + k0 + g) = *(bf16x8*)o;
    }
}

// ---- gating: one wave per token ----
__global__ void gating_kernel(const float* __restrict__ x, const float* __restrict__ gw,
                              int* __restrict__ topki, float* __restrict__ topkp,
                              float* __restrict__ imp) {
    int lane = threadIdx.x & 63;
    int t = blockIdx.x * 4 + (threadIdx.x >> 6);
    float a[NE];
#pragma unroll
    for (int e = 0; e < NE; ++e) a[e] = 0.f;
#pragma unroll
    for (int c = 0; c < 16; ++c) {
        float xv = x[(size_t)t * HID + c * 64 + lane];
#pragma unroll
        for (int e = 0; e < NE; ++e) a[e] += xv * gw[e * HID + c * 64 + lane];
    }
#pragma unroll
    for (int e = 0; e < NE; ++e) {
#pragma unroll
        for (int off = 32; off > 0; off >>= 1) a[e] += __shfl_xor(a[e], off, 64);
    }
    if (lane == 0) {
        float v0 = -1e30f, v1 = -1e30f; int e0 = 0, e1 = 0;
#pragma unroll
        for (int e = 0; e < NE; ++e) {
            if (a[e] > v0) { v1 = v0; e1 = e0; v0 = a[e]; e0 = e; }
            else if (a[e] > v1) { v1 = a[e]; e1 = e; }
        }
        float p0 = 1.f / (1.f + expf(v1 - v0));
        topki[2 * t] = e0; topki[2 * t + 1] = e1;
        topkp[2 * t] = p0; topkp[2 * t + 1] = 1.f - p0;
        float s = 0.f, pe[NE];
#pragma unroll
        for (int e = 0; e < NE; ++e) { pe[e] = expf(a[e] - v0); s += pe[e]; }
        float inv = 1.f / s;
#pragma unroll
        for (int e = 0; e < NE; ++e) atomicAdd(&imp[e], pe[e] * inv);
    }
}

// ---- bucket append ----
__global__ void compact_kernel(const int* __restrict__ topki, const float* __restrict__ topkp,
                               int* __restrict__ cnt, int* __restrict__ btok,
                               float* __restrict__ bprb) {
    int idx = blockIdx.x * 256 + threadIdx.x;
    int e = topki[idx];
    int pos = atomicAdd(&cnt[e], 1);
    btok[e * T_TOK + pos] = idx >> 1;
    bprb[e * T_TOK + pos] = topkp[idx];
}

// ---- offsets + aux loss ----
__global__ void finalize_kernel(const int* __restrict__ cnt, const float* __restrict__ imp,
                                int* __restrict__ offs, float* __restrict__ aux_out) {
    if (threadIdx.x == 0) {
        int off = 0; float s = 0.f;
        for (int e = 0; e < NE; ++e) {
            offs[e] = off; off += cnt[e];
            s += ((float)cnt[e] / (4096.f + 1e-9f)) * (imp[e] / 2048.f);
        }
        aux_out[0] = fminf(s * 8.f * 0.01f, 1.f);
    }
}

// ---- GEMM1: act = silu(X@W1) * (X@W3), gathered rows, 128x128 tile ----
__global__ __launch_bounds__(256, 2)
void gemm1_kernel(const u16* __restrict__ xb, const u16* __restrict__ w1t,
                  const u16* __restrict__ w3t, u16* __restrict__ act,
                  const int* __restrict__ btok, const int* __restrict__ cnt,
                  const int* __restrict__ offs) {
    int e = blockIdx.z;
    int n_e = cnt[e];
    int m0 = blockIdx.y * 128;
    if (m0 >= n_e) return;
    int nn0 = blockIdx.x * 128;
    int base = offs[e];

    __shared__ __align__(16) u16 As[128 * 40];
    __shared__ __align__(16) u16 B1s[128 * 40];
    __shared__ __align__(16) u16 B3s[128 * 40];

    int tid = threadIdx.x, lane = tid & 63, wv = tid >> 6;
    int wm = (wv >> 1) * 64, wn = (wv & 1) * 64;
    int l15 = lane & 15, quad = lane >> 4;

    f32x4 acc1[4][4] = {}, acc3[4][4] = {};

    for (int k0 = 0; k0 < HID; k0 += 32) {
#pragma unroll
        for (int p = 0; p < 2; ++p) {
            int idx = p * 256 + tid;
            int row = idx >> 2, sub = (idx & 3) * 8;
            int m = m0 + row;
            bf16x8 av = {};
            if (m < n_e) {
                int t = btok[e * T_TOK + m];
                av = *(const bf16x8*)(xb + (size_t)t * HID + k0 + sub);
            }
            *(bf16x8*)&As[row * 40 + sub] = av;
            *(bf16x8*)&B1s[row * 40 + sub] =
                *(const bf16x8*)(w1t + ((size_t)e * DFF + nn0 + row) * HID + k0 + sub);
            *(bf16x8*)&B3s[row * 40 + sub] =
                *(const bf16x8*)(w3t + ((size_t)e * DFF + nn0 + row) * HID + k0 + sub);
        }
        __syncthreads();
        bf16x8 af[4];
#pragma unroll
        for (int i = 0; i < 4; ++i)
            af[i] = *(const bf16x8*)&As[(wm + i * 16 + l15) * 40 + quad * 8];
#pragma unroll
        for (int j = 0; j < 4; ++j) {
            bf16x8 b1 = *(const bf16x8*)&B1s[(wn + j * 16 + l15) * 40 + quad * 8];
            bf16x8 b3 = *(const bf16x8*)&B3s[(wn + j * 16 + l15) * 40 + quad * 8];
#pragma unroll
            for (int i = 0; i < 4; ++i) {
                acc1[i][j] = __builtin_amdgcn_mfma_f32_16x16x32_bf16(af[i], b1, acc1[i][j], 0, 0, 0);
                acc3[i][j] = __builtin_amdgcn_mfma_f32_16x16x32_bf16(af[i], b3, acc3[i][j], 0, 0, 0);
            }
        }
        __syncthreads();
    }
#pragma unroll
    for (int i = 0; i < 4; ++i) {
#pragma unroll
        for (int r = 0; r < 4; ++r) {
            int m = m0 + wm + i * 16 + quad * 4 + r;
            if (m < n_e) {
#pragma unroll
                for (int j = 0; j < 4; ++j) {
                    float h1 = acc1[i][j][r], h3 = acc3[i][j][r];
                    float v = h1 / (1.f + expf(-h1)) * h3;   // silu(h1)*h3
                    act[(size_t)(base + m) * DFF + nn0 + wn + j * 16 + l15] = f2bf(v);
                }
            }
        }
    }
}

// ---- GEMM2: out[t] += p * (act @ W2), scatter via atomics ----
__global__ __launch_bounds__(256, 2)
void gemm2_kernel(const u16* __restrict__ act, const u16* __restrict__ w2t,
                  float* __restrict__ out, const int* __restrict__ btok,
                  const float* __restrict__ bprb, const int* __restrict__ cnt,
                  const int* __restrict__ offs) {
    int e = blockIdx.z;
    int n_e = cnt[e];
    int m0 = blockIdx.y * 128;
    if (m0 >= n_e) return;
    int nn0 = blockIdx.x * 128;
    int base = offs[e];

    __shared__ __align__(16) u16 As[128 * 40];
    __shared__ __align__(16) u16 Bs[128 * 40];

    int tid = threadIdx.x, lane = tid & 63, wv = tid >> 6;
    int wm = (wv >> 1) * 64, wn = (wv & 1) * 64;
    int l15 = lane & 15, quad = lane >> 4;

    f32x4 acc[4][4] = {};

    for (int k0 = 0; k0 < DFF; k0 += 32) {
#pragma unroll
        for (int p = 0; p < 2; ++p) {
            int idx = p * 256 + tid;
            int row = idx >> 2, sub = (idx & 3) * 8;
            int m = m0 + row;
            bf16x8 av = {};
            if (m < n_e)
                av = *(const bf16x8*)(act + (size_t)(base + m) * DFF + k0 + sub);
            *(bf16x8*)&As[row * 40 + sub] = av;
            *(bf16x8*)&Bs[row * 40 + sub] =
                *(const bf16x8*)(w2t + ((size_t)e * HID + nn0 + row) * DFF + k0 + sub);
        }
        __syncthreads();
        bf16x8 af[4];
#pragma unroll
        for (int i = 0; i < 4; ++i)
            af[i] = *(const bf16x8*)&As[(wm + i * 16 + l15) * 40 + quad * 8];
#pragma unroll
        for (int j = 0; j < 4; ++j) {
            bf16x8 bf = *(const bf16x8*)&Bs[(wn + j * 16 + l15) * 40 + quad * 8];
#pragma unroll
            for (int i = 0; i < 4; ++i)
                acc[i][j] = __builtin_amdgcn_mfma_f32_16x16x32_bf16(af[i], bf, acc[i][j], 0, 0, 0);
        }
        __syncthreads();
    }
#pragma unroll
    for (int i = 0; i < 4; ++i) {
#pragma unroll
        for (int r = 0; r < 4; ++r) {
            int m = m0 + wm + i * 16 + quad * 4 + r;
            if (m < n_e) {
                int t = btok[e * T_TOK + m];
                float p = bprb[e * T_TOK + m];
#pragma unroll
                for (int j = 0; j < 4; ++j)
                    atomicAdd(&out[(size_t)t * HID + nn0 + wn + j * 16 + l15], p * acc[i][j][r]);
            }
        }
    }
}

extern "C" void kernel_launch(void* const* d_in, const int* in_sizes, int n_in,
                              void* d_out, int out_size, void* d_ws, size_t ws_size,
                              hipStream_t stream) {
    if (ws_size < (size_t)WS_NEEDED) return;  // clean failure signature (0xAA output)

    const float* x  = (const float*)d_in[0];
    const float* gw = (const float*)d_in[1];
    const float* w1 = (const float*)d_in[2];
    const float* w3 = (const float*)d_in[3];
    const float* w2 = (const float*)d_in[4];
    float* out = (float*)d_out;

    char* ws = (char*)d_ws;
    int*   cnt   = (int*)(ws + OFF_CNT);
    float* imp   = (float*)(ws + OFF_IMP);
    int*   offs  = (int*)(ws + OFF_OFFS);
    int*   topki = (int*)(ws + OFF_TOPKI);
    float* topkp = (float*)(ws + OFF_TOPKP);
    int*   btok  = (int*)(ws + OFF_BTOK);
    float* bprb  = (float*)(ws + OFF_BPRB);
    u16*   xb    = (u16*)(ws + OFF_XB);
    u16*   w1t   = (u16*)(ws + OFF_W1T);
    u16*   w3t   = (u16*)(ws + OFF_W3T);
    u16*   w2t   = (u16*)(ws + OFF_W2T);
    u16*   actb  = (u16*)(ws + OFF_ACT);

    hipMemsetAsync(ws, 0, 256, stream);
    hipMemsetAsync(d_out, 0, (size_t)out_size * sizeof(float), stream);

    cvt_x_kernel<<<2048, 256, 0, stream>>>(x, xb);
    transpose_kernel<<<dim3(DFF / 64, HID / 64, NE), 256, 0, stream>>>(w1, w1t, HID, DFF);
    transpose_kernel<<<dim3(DFF / 64, HID / 64, NE), 256, 0, stream>>>(w3, w3t, HID, DFF);
    transpose_kernel<<<dim3(HID / 64, DFF / 64, NE), 256, 0, stream>>>(w2, w2t, DFF, HID);

    gating_kernel<<<T_TOK / 4, 256, 0, stream>>>(x, gw, topki, topkp, imp);
    compact_kernel<<<ROWS / 256, 256, 0, stream>>>(topki, topkp, cnt, btok, bprb);
    finalize_kernel<<<1, 64, 0, stream>>>(cnt, imp, offs, out + (size_t)T_TOK * HID);

    gemm1_kernel<<<dim3(DFF / 128, T_TOK / 128, NE), 256, 0, stream>>>(
        xb, w1t, w3t, actb, btok, cnt, offs);
    gemm2_kernel<<<dim3(HID / 128, T_TOK / 128, NE), 256, 0, stream>>>(
        actb, w2t, out, btok, bprb, cnt, offs);
}

// Round 2
// 527.499 us; speedup vs baseline: 1.5287x; 1.5287x over previous
//
#include <hip/hip_runtime.h>
#include <hip/hip_bf16.h>
#include <math.h>

// MoE FFN: T=2048 tokens, H=1024, F=2816, E=8, top-2, SwiGLU + aux loss.
// R2: (a) gating importance via LDS pre-reduce (atomics 16384->2048),
//     (b) GEMM staging via global_load_lds width=16, unpadded LDS stride 32.

#define T_TOK 2048
#define HID   1024
#define DFF   2816
#define NE    8
#define ROWS  4096   // T_TOK * TOP_K

typedef unsigned short u16;
typedef __attribute__((ext_vector_type(8))) short bf16x8;
typedef __attribute__((ext_vector_type(4))) float f32x4;

// ---- workspace layout (bytes) ----
#define OFF_CNT    0                       // int[8]
#define OFF_IMP    64                      // float[8]
#define OFF_OFFS   128                     // int[8]
#define OFF_TOPKI  256                     // int[4096]
#define OFF_TOPKP  (OFF_TOPKI + 16384)     // float[4096]
#define OFF_BTOK   (OFF_TOPKP + 16384)     // int[8][2048]
#define OFF_BPRB   (OFF_BTOK + 65536)      // float[8][2048]
#define OFF_XB     (OFF_BPRB + 65536)      // bf16[2048][1024]
#define OFF_W1T    (OFF_XB + 4194304)      // bf16[8][2816][1024]  (transposed)
#define OFF_W3T    (OFF_W1T + 46137344)
#define OFF_W2T    (OFF_W3T + 46137344)    // bf16[8][1024][2816]  (transposed)
#define OFF_ACT    (OFF_W2T + 46137344)    // bf16[4096][2816]
#define WS_NEEDED  (OFF_ACT + 23068672)    // ~158.2 MiB

__device__ __forceinline__ u16 f2bf(float f) {
    unsigned u = __float_as_uint(f);
    u = (u + 0x7fffu + ((u >> 16) & 1u)) >> 16;   // RNE
    return (u16)u;
}

// async global->LDS, 16B per lane; LDS dest must be wave-uniform base (+lane*16 implicit)
__device__ __forceinline__ void glds16(const void* g, void* l) {
    __builtin_amdgcn_global_load_lds(
        (const __attribute__((address_space(1))) unsigned int*)g,
        (__attribute__((address_space(3))) unsigned int*)l, 16, 0, 0);
}

// ---- fp32 -> bf16, x (no transpose) ----
__global__ void cvt_x_kernel(const float* __restrict__ x, u16* __restrict__ xb) {
    int i = blockIdx.x * 256 + threadIdx.x;          // over float4s
    float4 v = ((const float4*)x)[i];
    union { u16 s[4]; unsigned long long q; } o;
    o.s[0] = f2bf(v.x); o.s[1] = f2bf(v.y); o.s[2] = f2bf(v.z); o.s[3] = f2bf(v.w);
    ((unsigned long long*)xb)[i] = o.q;
}

// ---- fp32 [K][N] -> bf16 [N][K] transpose (per expert in grid.z) ----
__global__ void transpose_kernel(const float* __restrict__ in, u16* __restrict__ out,
                                 int K, int N) {
    __shared__ float tile[64][65];
    const float* ip = in + (size_t)blockIdx.z * K * N;
    u16* op = out + (size_t)blockIdx.z * K * N;
    int n0 = blockIdx.x * 64, k0 = blockIdx.y * 64;
    int tid = threadIdx.x;
#pragma unroll
    for (int p = 0; p < 4; ++p) {
        int row = p * 16 + (tid >> 4);       // k-local
        int v = (tid & 15) * 4;              // n-local
        float4 d = *(const float4*)(ip + (size_t)(k0 + row) * N + n0 + v);
        tile[row][v] = d.x; tile[row][v + 1] = d.y; tile[row][v + 2] = d.z; tile[row][v + 3] = d.w;
    }
    __syncthreads();
#pragma unroll
    for (int p = 0; p < 2; ++p) {
        int n = p * 32 + (tid >> 3);         // n-local
        int g = (tid & 7) * 8;               // k-local chunk
        u16 o[8];
#pragma unroll
        for (int j = 0; j < 8; ++j) o[j] = f2bf(tile[g + j][n]);
        *(bf16x8*)(op + (size_t)(n0 + n) * K + k0 + g) = *(bf16x8*)o;
    }
}

// ---- gating: one wave per token, 8 waves/block, LDS-reduced importance ----
__global__ void gating_kernel(const float* __restrict__ x, const float* __restrict__ gw,
                              int* __restrict__ topki, float* __restrict__ topkp,
                              float* __restrict__ imp) {
    __shared__ float s_imp[NE];
    int tid = threadIdx.x;
    if (tid < NE) s_imp[tid] = 0.f;
    __syncthreads();
    int lane = tid & 63;
    int t = blockIdx.x * 8 + (tid >> 6);
    float a[NE];
#pragma unroll
    for (int e = 0; e < NE; ++e) a[e] = 0.f;
#pragma unroll
    for (int c = 0; c < 16; ++c) {
        float xv = x[(size_t)t * HID + c * 64 + lane];
#pragma unroll
        for (int e = 0; e < NE; ++e) a[e] += xv * gw[e * HID + c * 64 + lane];
    }
#pragma unroll
    for (int e = 0; e < NE; ++e) {
#pragma unroll
        for (int off = 32; off > 0; off >>= 1) a[e] += __shfl_xor(a[e], off, 64);
    }
    if (lane == 0) {
        float v0 = -1e30f, v1 = -1e30f; int e0 = 0, e1 = 0;
#pragma unroll
        for (int e = 0; e < NE; ++e) {
            if (a[e] > v0) { v1 = v0; e1 = e0; v0 = a[e]; e0 = e; }
            else if (a[e] > v1) { v1 = a[e]; e1 = e; }
        }
        float p0 = 1.f / (1.f + expf(v1 - v0));
        topki[2 * t] = e0; topki[2 * t + 1] = e1;
        topkp[2 * t] = p0; topkp[2 * t + 1] = 1.f - p0;
        float s = 0.f, pe[NE];
#pragma unroll
        for (int e = 0; e < NE; ++e) { pe[e] = expf(a[e] - v0); s += pe[e]; }
        float inv = 1.f / s;
#pragma unroll
        for (int e = 0; e < NE; ++e) atomicAdd(&s_imp[e], pe[e] * inv);
    }
    __syncthreads();
    if (tid < NE) atomicAdd(&imp[tid], s_imp[tid]);
}

// ---- bucket append ----
__global__ void compact_kernel(const int* __restrict__ topki, const float* __restrict__ topkp,
                               int* __restrict__ cnt, int* __restrict__ btok,
                               float* __restrict__ bprb) {
    int idx = blockIdx.x * 256 + threadIdx.x;
    int e = topki[idx];
    int pos = atomicAdd(&cnt[e], 1);
    btok[e * T_TOK + pos] = idx >> 1;
    bprb[e * T_TOK + pos] = topkp[idx];
}

// ---- offsets + aux loss ----
__global__ void finalize_kernel(const int* __restrict__ cnt, const float* __restrict__ imp,
                                int* __restrict__ offs, float* __restrict__ aux_out) {
    if (threadIdx.x == 0) {
        int off = 0; float s = 0.f;
        for (int e = 0; e < NE; ++e) {
            offs[e] = off; off += cnt[e];
            s += ((float)cnt[e] / (4096.f + 1e-9f)) * (imp[e] / 2048.f);
        }
        aux_out[0] = fminf(s * 8.f * 0.01f, 1.f);
    }
}

// ---- GEMM1: act = silu(X@W1) * (X@W3), gathered rows, 128x128 tile ----
// LDS stride 32 shorts (unpadded) — required by global_load_lds lane order.
__global__ __launch_bounds__(256, 2)
void gemm1_kernel(const u16* __restrict__ xb, const u16* __restrict__ w1t,
                  const u16* __restrict__ w3t, u16* __restrict__ act,
                  const int* __restrict__ btok, const int* __restrict__ cnt,
                  const int* __restrict__ offs) {
    int e = blockIdx.z;
    int n_e = cnt[e];
    int m0 = blockIdx.y * 128;
    if (m0 >= n_e) return;
    int nn0 = blockIdx.x * 128;
    int base = offs[e];

    __shared__ __align__(16) u16 As[128 * 32];
    __shared__ __align__(16) u16 B1s[128 * 32];
    __shared__ __align__(16) u16 B3s[128 * 32];

    int tid = threadIdx.x, lane = tid & 63, wv = tid >> 6;
    int wm = (wv >> 1) * 64, wn = (wv & 1) * 64;
    int l15 = lane & 15, quad = lane >> 4;

    // hoist gathered row pointers (each thread stages 2 rows x 8 shorts per K-iter)
    int row0 = tid >> 2, row1 = 64 + row0;
    int sub = (tid & 3) * 8;
    int t0 = (m0 + row0 < n_e) ? btok[e * T_TOK + m0 + row0] : 0;
    int t1 = (m0 + row1 < n_e) ? btok[e * T_TOK + m0 + row1] : 0;
    const u16* ga0 = xb + (size_t)t0 * HID + sub;
    const u16* ga1 = xb + (size_t)t1 * HID + sub;
    const u16* g10 = w1t + ((size_t)e * DFF + nn0 + row0) * HID + sub;
    const u16* g11 = w1t + ((size_t)e * DFF + nn0 + row1) * HID + sub;
    const u16* g30 = w3t + ((size_t)e * DFF + nn0 + row0) * HID + sub;
    const u16* g31 = w3t + ((size_t)e * DFF + nn0 + row1) * HID + sub;
    u16* la0 = As  + (size_t)(wv * 64) * 8;       // wave-uniform LDS bases
    u16* la1 = As  + (size_t)(256 + wv * 64) * 8;
    u16* l10 = B1s + (size_t)(wv * 64) * 8;
    u16* l11 = B1s + (size_t)(256 + wv * 64) * 8;
    u16* l30 = B3s + (size_t)(wv * 64) * 8;
    u16* l31 = B3s + (size_t)(256 + wv * 64) * 8;

    f32x4 acc1[4][4] = {}, acc3[4][4] = {};

    for (int k0 = 0; k0 < HID; k0 += 32) {
        glds16(ga0 + k0, la0); glds16(ga1 + k0, la1);
        glds16(g10 + k0, l10); glds16(g11 + k0, l11);
        glds16(g30 + k0, l30); glds16(g31 + k0, l31);
        __syncthreads();
        bf16x8 af[4];
#pragma unroll
        for (int i = 0; i < 4; ++i)
            af[i] = *(const bf16x8*)&As[(wm + i * 16 + l15) * 32 + quad * 8];
#pragma unroll
        for (int j = 0; j < 4; ++j) {
            bf16x8 b1 = *(const bf16x8*)&B1s[(wn + j * 16 + l15) * 32 + quad * 8];
            bf16x8 b3 = *(const bf16x8*)&B3s[(wn + j * 16 + l15) * 32 + quad * 8];
#pragma unroll
            for (int i = 0; i < 4; ++i) {
                acc1[i][j] = __builtin_amdgcn_mfma_f32_16x16x32_bf16(af[i], b1, acc1[i][j], 0, 0, 0);
                acc3[i][j] = __builtin_amdgcn_mfma_f32_16x16x32_bf16(af[i], b3, acc3[i][j], 0, 0, 0);
            }
        }
        __syncthreads();
    }
#pragma unroll
    for (int i = 0; i < 4; ++i) {
#pragma unroll
        for (int r = 0; r < 4; ++r) {
            int m = m0 + wm + i * 16 + quad * 4 + r;
            if (m < n_e) {
#pragma unroll
                for (int j = 0; j < 4; ++j) {
                    float h1 = acc1[i][j][r], h3 = acc3[i][j][r];
                    float v = h1 / (1.f + expf(-h1)) * h3;   // silu(h1)*h3
                    act[(size_t)(base + m) * DFF + nn0 + wn + j * 16 + l15] = f2bf(v);
                }
            }
        }
    }
}

// ---- GEMM2: out[t] += p * (act @ W2), scatter via atomics ----
__global__ __launch_bounds__(256, 2)
void gemm2_kernel(const u16* __restrict__ act, const u16* __restrict__ w2t,
                  float* __restrict__ out, const int* __restrict__ btok,
                  const float* __restrict__ bprb, const int* __restrict__ cnt,
                  const int* __restrict__ offs) {
    int e = blockIdx.z;
    int n_e = cnt[e];
    int m0 = blockIdx.y * 128;
    if (m0 >= n_e) return;
    int nn0 = blockIdx.x * 128;
    int base = offs[e];

    __shared__ __align__(16) u16 As[128 * 32];
    __shared__ __align__(16) u16 Bs[128 * 32];

    int tid = threadIdx.x, lane = tid & 63, wv = tid >> 6;
    int wm = (wv >> 1) * 64, wn = (wv & 1) * 64;
    int l15 = lane & 15, quad = lane >> 4;

    int row0 = tid >> 2, row1 = 64 + row0;
    int sub = (tid & 3) * 8;
    int r0c = (m0 + row0 < n_e) ? (base + m0 + row0) : base;   // clamp: valid mem, masked later
    int r1c = (m0 + row1 < n_e) ? (base + m0 + row1) : base;
    const u16* ga0 = act + (size_t)r0c * DFF + sub;
    const u16* ga1 = act + (size_t)r1c * DFF + sub;
    const u16* gb0 = w2t + ((size_t)e * HID + nn0 + row0) * DFF + sub;
    const u16* gb1 = w2t + ((size_t)e * HID + nn0 + row1) * DFF + sub;
    u16* la0 = As + (size_t)(wv * 64) * 8;
    u16* la1 = As + (size_t)(256 + wv * 64) * 8;
    u16* lb0 = Bs + (size_t)(wv * 64) * 8;
    u16* lb1 = Bs + (size_t)(256 + wv * 64) * 8;

    f32x4 acc[4][4] = {};

    for (int k0 = 0; k0 < DFF; k0 += 32) {
        glds16(ga0 + k0, la0); glds16(ga1 + k0, la1);
        glds16(gb0 + k0, lb0); glds16(gb1 + k0, lb1);
        __syncthreads();
        bf16x8 af[4];
#pragma unroll
        for (int i = 0; i < 4; ++i)
            af[i] = *(const bf16x8*)&As[(wm + i * 16 + l15) * 32 + quad * 8];
#pragma unroll
        for (int j = 0; j < 4; ++j) {
            bf16x8 bf = *(const bf16x8*)&Bs[(wn + j * 16 + l15) * 32 + quad * 8];
#pragma unroll
            for (int i = 0; i < 4; ++i)
                acc[i][j] = __builtin_amdgcn_mfma_f32_16x16x32_bf16(af[i], bf, acc[i][j], 0, 0, 0);
        }
        __syncthreads();
    }
#pragma unroll
    for (int i = 0; i < 4; ++i) {
#pragma unroll
        for (int r = 0; r < 4; ++r) {
            int m = m0 + wm + i * 16 + quad * 4 + r;
            if (m < n_e) {
                int t = btok[e * T_TOK + m];
                float p = bprb[e * T_TOK + m];
#pragma unroll
                for (int j = 0; j < 4; ++j)
                    atomicAdd(&out[(size_t)t * HID + nn0 + wn + j * 16 + l15], p * acc[i][j][r]);
            }
        }
    }
}

extern "C" void kernel_launch(void* const* d_in, const int* in_sizes, int n_in,
                              void* d_out, int out_size, void* d_ws, size_t ws_size,
                              hipStream_t stream) {
    if (ws_size < (size_t)WS_NEEDED) return;  // clean failure signature (0xAA output)

    const float* x  = (const float*)d_in[0];
    const float* gw = (const float*)d_in[1];
    const float* w1 = (const float*)d_in[2];
    const float* w3 = (const float*)d_in[3];
    const float* w2 = (const float*)d_in[4];
    float* out = (float*)d_out;

    char* ws = (char*)d_ws;
    int*   cnt   = (int*)(ws + OFF_CNT);
    float* imp   = (float*)(ws + OFF_IMP);
    int*   offs  = (int*)(ws + OFF_OFFS);
    int*   topki = (int*)(ws + OFF_TOPKI);
    float* topkp = (float*)(ws + OFF_TOPKP);
    int*   btok  = (int*)(ws + OFF_BTOK);
    float* bprb  = (float*)(ws + OFF_BPRB);
    u16*   xb    = (u16*)(ws + OFF_XB);
    u16*   w1t   = (u16*)(ws + OFF_W1T);
    u16*   w3t   = (u16*)(ws + OFF_W3T);
    u16*   w2t   = (u16*)(ws + OFF_W2T);
    u16*   actb  = (u16*)(ws + OFF_ACT);

    hipMemsetAsync(ws, 0, 256, stream);
    hipMemsetAsync(d_out, 0, (size_t)out_size * sizeof(float), stream);

    cvt_x_kernel<<<2048, 256, 0, stream>>>(x, xb);
    transpose_kernel<<<dim3(DFF / 64, HID / 64, NE), 256, 0, stream>>>(w1, w1t, HID, DFF);
    transpose_kernel<<<dim3(DFF / 64, HID / 64, NE), 256, 0, stream>>>(w3, w3t, HID, DFF);
    transpose_kernel<<<dim3(HID / 64, DFF / 64, NE), 256, 0, stream>>>(w2, w2t, DFF, HID);

    gating_kernel<<<T_TOK / 8, 512, 0, stream>>>(x, gw, topki, topkp, imp);
    compact_kernel<<<ROWS / 256, 256, 0, stream>>>(topki, topkp, cnt, btok, bprb);
    finalize_kernel<<<1, 64, 0, stream>>>(cnt, imp, offs, out + (size_t)T_TOK * HID);

    gemm1_kernel<<<dim3(DFF / 128, T_TOK / 128, NE), 256, 0, stream>>>(
        xb, w1t, w3t, actb, btok, cnt, offs);
    gemm2_kernel<<<dim3(HID / 128, T_TOK / 128, NE), 256, 0, stream>>>(
        actb, w2t, out, btok, bprb, cnt, offs);
}

// Round 3
// 519.701 us; speedup vs baseline: 1.5517x; 1.0150x over previous
//
#include <hip/hip_runtime.h>
#include <hip/hip_bf16.h>
#include <math.h>

// MoE FFN: T=2048 tokens, H=1024, F=2816, E=8, top-2, SwiGLU + aux loss.
// R3: gemm2 -> 64x128 tiles (2 blocks/CU), no atomics (ybuf + combine),
//     LDS quad-swizzle in both GEMMs (2-way bank aliasing = free).

#define T_TOK 2048
#define HID   1024
#define DFF   2816
#define NE    8
#define ROWS  4096   // T_TOK * TOP_K

typedef unsigned short u16;
typedef __attribute__((ext_vector_type(8))) short bf16x8;
typedef __attribute__((ext_vector_type(4))) float f32x4;

// ---- workspace layout (bytes) ----
#define OFF_CNT    0                       // int[8]
#define OFF_IMP    64                      // float[8]
#define OFF_OFFS   128                     // int[8]
#define OFF_TOPKI  256                     // int[4096]
#define OFF_TOPKP  (OFF_TOPKI + 16384)     // float[4096]
#define OFF_BTOK   (OFF_TOPKP + 16384)     // int[8][2048]
#define OFF_EPOS   (OFF_BTOK + 65536)      // int[4096] (expert<<11 | pos)
#define OFF_XB     (OFF_EPOS + 65536)      // bf16[2048][1024]
#define OFF_W1T    (OFF_XB + 4194304)      // bf16[8][2816][1024]  (transposed)
#define OFF_W3T    (OFF_W1T + 46137344)
#define OFF_W2T    (OFF_W3T + 46137344)    // bf16[8][1024][2816]  (transposed)
#define OFF_ACT    (OFF_W2T + 46137344)    // bf16[4096][2816]
#define WS_NEEDED  (OFF_ACT + 23068672)    // ~158.2 MiB
// ybuf (f32[4096][1024] = 16.8 MB) overlays OFF_W1T: w1t is dead after gemm1.

__device__ __forceinline__ u16 f2bf(float f) {
    unsigned u = __float_as_uint(f);
    u = (u + 0x7fffu + ((u >> 16) & 1u)) >> 16;   // RNE
    return (u16)u;
}

// async global->LDS, 16B per lane; LDS dest wave-uniform base (+lane*16 implicit)
__device__ __forceinline__ void glds16(const void* g, void* l) {
    __builtin_amdgcn_global_load_lds(
        (const __attribute__((address_space(1))) unsigned int*)g,
        (__attribute__((address_space(3))) unsigned int*)l, 16, 0, 0);
}

// ---- fp32 -> bf16, x ----
__global__ void cvt_x_kernel(const float* __restrict__ x, u16* __restrict__ xb) {
    int i = blockIdx.x * 256 + threadIdx.x;
    float4 v = ((const float4*)x)[i];
    union { u16 s[4]; unsigned long long q; } o;
    o.s[0] = f2bf(v.x); o.s[1] = f2bf(v.y); o.s[2] = f2bf(v.z); o.s[3] = f2bf(v.w);
    ((unsigned long long*)xb)[i] = o.q;
}

// ---- fp32 [K][N] -> bf16 [N][K] transpose (per expert in grid.z) ----
__global__ void transpose_kernel(const float* __restrict__ in, u16* __restrict__ out,
                                 int K, int N) {
    __shared__ float tile[64][65];
    const float* ip = in + (size_t)blockIdx.z * K * N;
    u16* op = out + (size_t)blockIdx.z * K * N;
    int n0 = blockIdx.x * 64, k0 = blockIdx.y * 64;
    int tid = threadIdx.x;
#pragma unroll
    for (int p = 0; p < 4; ++p) {
        int row = p * 16 + (tid >> 4);
        int v = (tid & 15) * 4;
        float4 d = *(const float4*)(ip + (size_t)(k0 + row) * N + n0 + v);
        tile[row][v] = d.x; tile[row][v + 1] = d.y; tile[row][v + 2] = d.z; tile[row][v + 3] = d.w;
    }
    __syncthreads();
#pragma unroll
    for (int p = 0; p < 2; ++p) {
        int n = p * 32 + (tid >> 3);
        int g = (tid & 7) * 8;
        u16 o[8];
#pragma unroll
        for (int j = 0; j < 8; ++j) o[j] = f2bf(tile[g + j][n]);
        *(bf16x8*)(op + (size_t)(n0 + n) * K + k0 + g) = *(bf16x8*)o;
    }
}

// ---- gating: one wave per token, LDS-reduced importance ----
__global__ void gating_kernel(const float* __restrict__ x, const float* __restrict__ gw,
                              int* __restrict__ topki, float* __restrict__ topkp,
                              float* __restrict__ imp) {
    __shared__ float s_imp[NE];
    int tid = threadIdx.x;
    if (tid < NE) s_imp[tid] = 0.f;
    __syncthreads();
    int lane = tid & 63;
    int t = blockIdx.x * 8 + (tid >> 6);
    float a[NE];
#pragma unroll
    for (int e = 0; e < NE; ++e) a[e] = 0.f;
#pragma unroll
    for (int c = 0; c < 16; ++c) {
        float xv = x[(size_t)t * HID + c * 64 + lane];
#pragma unroll
        for (int e = 0; e < NE; ++e) a[e] += xv * gw[e * HID + c * 64 + lane];
    }
#pragma unroll
    for (int e = 0; e < NE; ++e) {
#pragma unroll
        for (int off = 32; off > 0; off >>= 1) a[e] += __shfl_xor(a[e], off, 64);
    }
    if (lane == 0) {
        float v0 = -1e30f, v1 = -1e30f; int e0 = 0, e1 = 0;
#pragma unroll
        for (int e = 0; e < NE; ++e) {
            if (a[e] > v0) { v1 = v0; e1 = e0; v0 = a[e]; e0 = e; }
            else if (a[e] > v1) { v1 = a[e]; e1 = e; }
        }
        float p0 = 1.f / (1.f + expf(v1 - v0));
        topki[2 * t] = e0; topki[2 * t + 1] = e1;
        topkp[2 * t] = p0; topkp[2 * t + 1] = 1.f - p0;
        float s = 0.f, pe[NE];
#pragma unroll
        for (int e = 0; e < NE; ++e) { pe[e] = expf(a[e] - v0); s += pe[e]; }
        float inv = 1.f / s;
#pragma unroll
        for (int e = 0; e < NE; ++e) atomicAdd(&s_imp[e], pe[e] * inv);
    }
    __syncthreads();
    if (tid < NE) atomicAdd(&imp[tid], s_imp[tid]);
}

// ---- bucket append + epos record ----
__global__ void compact_kernel(const int* __restrict__ topki,
                               int* __restrict__ cnt, int* __restrict__ btok,
                               int* __restrict__ epos) {
    int idx = blockIdx.x * 256 + threadIdx.x;
    int e = topki[idx];
    int pos = atomicAdd(&cnt[e], 1);
    btok[e * T_TOK + pos] = idx >> 1;
    epos[idx] = (e << 11) | pos;
}

// ---- offsets + aux loss ----
__global__ void finalize_kernel(const int* __restrict__ cnt, const float* __restrict__ imp,
                                int* __restrict__ offs, float* __restrict__ aux_out) {
    if (threadIdx.x == 0) {
        int off = 0; float s = 0.f;
        for (int e = 0; e < NE; ++e) {
            offs[e] = off; off += cnt[e];
            s += ((float)cnt[e] / (4096.f + 1e-9f)) * (imp[e] / 2048.f);
        }
        aux_out[0] = fminf(s * 8.f * 0.01f, 1.f);
    }
}

// ---- GEMM1: act = silu(X@W1) * (X@W3), 128x128 tile, swizzled LDS ----
__global__ __launch_bounds__(256, 2)
void gemm1_kernel(const u16* __restrict__ xb, const u16* __restrict__ w1t,
                  const u16* __restrict__ w3t, u16* __restrict__ act,
                  const int* __restrict__ btok, const int* __restrict__ cnt,
                  const int* __restrict__ offs) {
    int e = blockIdx.z;
    int n_e = cnt[e];
    int m0 = blockIdx.y * 128;
    if (m0 >= n_e) return;
    int nn0 = blockIdx.x * 128;
    int base = offs[e];

    __shared__ __align__(16) u16 As[128 * 32];
    __shared__ __align__(16) u16 B1s[128 * 32];
    __shared__ __align__(16) u16 B3s[128 * 32];

    int tid = threadIdx.x, lane = tid & 63, wv = tid >> 6;
    int wm = (wv >> 1) * 64, wn = (wv & 1) * 64;
    int l15 = lane & 15, quad = lane >> 4;

    int row0 = tid >> 2, row1 = 64 + row0;
    int q = (tid & 3) ^ ((tid >> 3) & 3);    // swizzled global 16B-quad
    int sub = q * 8;
    int t0 = (m0 + row0 < n_e) ? btok[e * T_TOK + m0 + row0] : 0;
    int t1 = (m0 + row1 < n_e) ? btok[e * T_TOK + m0 + row1] : 0;
    const u16* ga0 = xb + (size_t)t0 * HID + sub;
    const u16* ga1 = xb + (size_t)t1 * HID + sub;
    const u16* g10 = w1t + ((size_t)e * DFF + nn0 + row0) * HID + sub;
    const u16* g11 = w1t + ((size_t)e * DFF + nn0 + row1) * HID + sub;
    const u16* g30 = w3t + ((size_t)e * DFF + nn0 + row0) * HID + sub;
    const u16* g31 = w3t + ((size_t)e * DFF + nn0 + row1) * HID + sub;
    u16* la0 = As  + (wv * 64) * 8;
    u16* la1 = As  + (256 + wv * 64) * 8;
    u16* l10 = B1s + (wv * 64) * 8;
    u16* l11 = B1s + (256 + wv * 64) * 8;
    u16* l30 = B3s + (wv * 64) * 8;
    u16* l31 = B3s + (256 + wv * 64) * 8;

    f32x4 acc1[4][4] = {}, acc3[4][4] = {};

    for (int k0 = 0; k0 < HID; k0 += 32) {
        glds16(ga0 + k0, la0); glds16(ga1 + k0, la1);
        glds16(g10 + k0, l10); glds16(g11 + k0, l11);
        glds16(g30 + k0, l30); glds16(g31 + k0, l31);
        __syncthreads();
        bf16x8 af[4];
#pragma unroll
        for (int i = 0; i < 4; ++i) {
            int R = wm + i * 16 + l15;
            af[i] = *(const bf16x8*)&As[R * 32 + (quad ^ ((R >> 1) & 3)) * 8];
        }
#pragma unroll
        for (int j = 0; j < 4; ++j) {
            int R = wn + j * 16 + l15;
            int so = R * 32 + (quad ^ ((R >> 1) & 3)) * 8;
            bf16x8 b1 = *(const bf16x8*)&B1s[so];
            bf16x8 b3 = *(const bf16x8*)&B3s[so];
#pragma unroll
            for (int i = 0; i < 4; ++i) {
                acc1[i][j] = __builtin_amdgcn_mfma_f32_16x16x32_bf16(af[i], b1, acc1[i][j], 0, 0, 0);
                acc3[i][j] = __builtin_amdgcn_mfma_f32_16x16x32_bf16(af[i], b3, acc3[i][j], 0, 0, 0);
            }
        }
        __syncthreads();
    }
#pragma unroll
    for (int i = 0; i < 4; ++i) {
#pragma unroll
        for (int r = 0; r < 4; ++r) {
            int m = m0 + wm + i * 16 + quad * 4 + r;
            if (m < n_e) {
#pragma unroll
                for (int j = 0; j < 4; ++j) {
                    float h1 = acc1[i][j][r], h3 = acc3[i][j][r];
                    float v = h1 / (1.f + expf(-h1)) * h3;   // silu(h1)*h3
                    act[(size_t)(base + m) * DFF + nn0 + wn + j * 16 + l15] = f2bf(v);
                }
            }
        }
    }
}

// ---- GEMM2: ybuf[row] = act[row] @ W2 (per bucket row), 64x128 tile ----
__global__ __launch_bounds__(256, 4)
void gemm2_kernel(const u16* __restrict__ act, const u16* __restrict__ w2t,
                  float* __restrict__ ybuf, const int* __restrict__ cnt,
                  const int* __restrict__ offs) {
    int e = blockIdx.z;
    int n_e = cnt[e];
    int m0 = blockIdx.y * 64;
    if (m0 >= n_e) return;
    int nn0 = blockIdx.x * 128;
    int base = offs[e];

    __shared__ __align__(16) u16 As[64 * 32];
    __shared__ __align__(16) u16 Bs[128 * 32];

    int tid = threadIdx.x, lane = tid & 63, wv = tid >> 6;
    int wn = wv * 32;
    int l15 = lane & 15, quad = lane >> 4;

    int row0 = tid >> 2;
    int q = (tid & 3) ^ ((tid >> 3) & 3);
    int sub = q * 8;
    int ra = (m0 + row0 < n_e) ? (base + m0 + row0) : base;
    const u16* ga0 = act + (size_t)ra * DFF + sub;
    const u16* gb0 = w2t + ((size_t)e * HID + nn0 + row0) * DFF + sub;
    const u16* gb1 = w2t + ((size_t)e * HID + nn0 + 64 + row0) * DFF + sub;
    u16* la0 = As + (wv * 64) * 8;
    u16* lb0 = Bs + (wv * 64) * 8;
    u16* lb1 = Bs + (256 + wv * 64) * 8;

    f32x4 acc[4][2] = {};

    for (int k0 = 0; k0 < DFF; k0 += 32) {
        glds16(ga0 + k0, la0);
        glds16(gb0 + k0, lb0); glds16(gb1 + k0, lb1);
        __syncthreads();
        bf16x8 af[4];
#pragma unroll
        for (int i = 0; i < 4; ++i) {
            int R = i * 16 + l15;
            af[i] = *(const bf16x8*)&As[R * 32 + (quad ^ ((R >> 1) & 3)) * 8];
        }
#pragma unroll
        for (int j = 0; j < 2; ++j) {
            int R = wn + j * 16 + l15;
            bf16x8 bf = *(const bf16x8*)&Bs[R * 32 + (quad ^ ((R >> 1) & 3)) * 8];
#pragma unroll
            for (int i = 0; i < 4; ++i)
                acc[i][j] = __builtin_amdgcn_mfma_f32_16x16x32_bf16(af[i], bf, acc[i][j], 0, 0, 0);
        }
        __syncthreads();
    }
#pragma unroll
    for (int i = 0; i < 4; ++i) {
#pragma unroll
        for (int r = 0; r < 4; ++r) {
            int m = m0 + i * 16 + quad * 4 + r;
            if (m < n_e) {
#pragma unroll
                for (int j = 0; j < 2; ++j)
                    ybuf[(size_t)(base + m) * HID + nn0 + wn + j * 16 + l15] = acc[i][j][r];
            }
        }
    }
}

// ---- combine: out[t] = p0*ybuf[r0] + p1*ybuf[r1] ----
__global__ void combine_kernel(const float* __restrict__ ybuf, const int* __restrict__ epos,
                               const float* __restrict__ topkp, const int* __restrict__ offs,
                               float* __restrict__ out) {
    int t = blockIdx.x;
    int c = threadIdx.x * 4;
    int ep0 = epos[2 * t], ep1 = epos[2 * t + 1];
    int r0 = offs[ep0 >> 11] + (ep0 & 2047);
    int r1 = offs[ep1 >> 11] + (ep1 & 2047);
    float p0 = topkp[2 * t], p1 = topkp[2 * t + 1];
    float4 a = *(const float4*)&ybuf[(size_t)r0 * HID + c];
    float4 b = *(const float4*)&ybuf[(size_t)r1 * HID + c];
    float4 o;
    o.x = p0 * a.x + p1 * b.x; o.y = p0 * a.y + p1 * b.y;
    o.z = p0 * a.z + p1 * b.z; o.w = p0 * a.w + p1 * b.w;
    *(float4*)&out[(size_t)t * HID + c] = o;
}

extern "C" void kernel_launch(void* const* d_in, const int* in_sizes, int n_in,
                              void* d_out, int out_size, void* d_ws, size_t ws_size,
                              hipStream_t stream) {
    if (ws_size < (size_t)WS_NEEDED) return;  // clean failure signature (0xAA output)

    const float* x  = (const float*)d_in[0];
    const float* gw = (const float*)d_in[1];
    const float* w1 = (const float*)d_in[2];
    const float* w3 = (const float*)d_in[3];
    const float* w2 = (const float*)d_in[4];
    float* out = (float*)d_out;

    char* ws = (char*)d_ws;
    int*   cnt   = (int*)(ws + OFF_CNT);
    float* imp   = (float*)(ws + OFF_IMP);
    int*   offs  = (int*)(ws + OFF_OFFS);
    int*   topki = (int*)(ws + OFF_TOPKI);
    float* topkp = (float*)(ws + OFF_TOPKP);
    int*   btok  = (int*)(ws + OFF_BTOK);
    int*   epos  = (int*)(ws + OFF_EPOS);
    u16*   xb    = (u16*)(ws + OFF_XB);
    u16*   w1t   = (u16*)(ws + OFF_W1T);
    u16*   w3t   = (u16*)(ws + OFF_W3T);
    u16*   w2t   = (u16*)(ws + OFF_W2T);
    u16*   actb  = (u16*)(ws + OFF_ACT);
    float* ybuf  = (float*)(ws + OFF_W1T);   // overlay: w1t dead after gemm1

    hipMemsetAsync(ws, 0, 256, stream);

    cvt_x_kernel<<<2048, 256, 0, stream>>>(x, xb);
    transpose_kernel<<<dim3(DFF / 64, HID / 64, NE), 256, 0, stream>>>(w1, w1t, HID, DFF);
    transpose_kernel<<<dim3(DFF / 64, HID / 64, NE), 256, 0, stream>>>(w3, w3t, HID, DFF);
    transpose_kernel<<<dim3(HID / 64, DFF / 64, NE), 256, 0, stream>>>(w2, w2t, DFF, HID);

    gating_kernel<<<T_TOK / 8, 512, 0, stream>>>(x, gw, topki, topkp, imp);
    compact_kernel<<<ROWS / 256, 256, 0, stream>>>(topki, cnt, btok, epos);
    finalize_kernel<<<1, 64, 0, stream>>>(cnt, imp, offs, out + (size_t)T_TOK * HID);

    gemm1_kernel<<<dim3(DFF / 128, T_TOK / 128, NE), 256, 0, stream>>>(
        xb, w1t, w3t, actb, btok, cnt, offs);
    gemm2_kernel<<<dim3(HID / 128, T_TOK / 64, NE), 256, 0, stream>>>(
        actb, w2t, ybuf, cnt, offs);
    combine_kernel<<<T_TOK, 256, 0, stream>>>(ybuf, epos, topkp, offs, out);
}